// Round 4
// baseline (179.053 us; speedup 1.0000x reference)
//
#include <hip/hip_runtime.h>
#include <math.h>

#define TOKENS 16384
#define DIM 2048
#define NE 8
#define BLOCK 1024
#define GRID 256               // 256 blocks x 64 tokens = 16384
#define NCHUNK (DIM / 256)     // 8 k-chunks of 64 float4

__launch_bounds__(BLOCK, 4)
__global__ void router_kernel(const float* __restrict__ x,
                              const float* __restrict__ w_g,
                              const float* __restrict__ w_noise,
                              const float* __restrict__ eps,
                              float* __restrict__ out)
{
    __shared__ float wlds[16 * DIM];   // 128 KiB: rows 0..7 = w_g, 8..15 = w_noise
    __shared__ float nbuf[8][64];      // 2 KiB: [pair][e*8+t] noise contribution

    const int tid = threadIdx.x;

    // ---- stage weights (coalesced float4) ----
    {
        const float4* g4 = (const float4*)w_g;
        const float4* n4 = (const float4*)w_noise;
        float4* l4 = (float4*)wlds;
        #pragma unroll
        for (int i = tid; i < (NE * DIM) / 4; i += BLOCK) {
            l4[i] = g4[i];
            l4[i + (NE * DIM) / 4] = n4[i];
        }
    }
    __syncthreads();

    const int lane  = tid & 63;
    const int wv    = tid >> 6;          // 0..15
    const int pair  = wv >> 1;           // 0..7
    const int noisy = wv & 1;            // even wave: gate rows; odd wave: noise rows
    const int tok0  = blockIdx.x * 64 + pair * 8;

    const float4* x4  = (const float4*)x;
    const float4* wl4 = (const float4*)wlds + (noisy ? (NE * DIM / 4) : 0);

    // V[r*8+t]: partial dot of this wave's row r (0..7) with token tok0+t
    float V[64];
    #pragma unroll
    for (int v = 0; v < 64; ++v) V[v] = 0.f;

    #pragma unroll
    for (int k = 0; k < NCHUNK; ++k) {
        float4 xv[8];
        #pragma unroll
        for (int t = 0; t < 8; ++t)
            xv[t] = x4[(tok0 + t) * (DIM / 4) + k * 64 + lane];
        #pragma unroll
        for (int r = 0; r < 8; ++r) {
            const float4 w = wl4[r * (DIM / 4) + k * 64 + lane];
            #pragma unroll
            for (int t = 0; t < 8; ++t) {
                float a = V[r * 8 + t];
                a = fmaf(xv[t].x, w.x, a);
                a = fmaf(xv[t].y, w.y, a);
                a = fmaf(xv[t].z, w.z, a);
                a = fmaf(xv[t].w, w.w, a);
                V[r * 8 + t] = a;
            }
        }
    }

    // ---- pack-halving reduction (validated in R3): lane L ends with sum of V[L] ----
    #pragma unroll
    for (int s = 0; s < 6; ++s) {
        const int m = 1 << s;
        const int n = 64 >> s;
        #pragma unroll
        for (int j = 0; j < n / 2; ++j) {
            const float A = V[2 * j];
            const float B = V[2 * j + 1];
            const float As = __shfl_xor(A, m, 64);
            const float Bs = __shfl_xor(B, m, 64);
            V[j] = (lane & m) ? (B + Bs) : (A + As);
        }
    }
    const float mine = V[0];   // lane L: row (L>>3), token tok0 + (L&7)

    const int e = lane >> 3;
    const int t = lane & 7;

    if (noisy) {
        // stable softplus, scale by eps, hand to pair-wave via LDS
        const float ev = eps[(tok0 + t) * NE + e];
        const float sp = fmaxf(mine, 0.f) + log1pf(expf(-fabsf(mine)));
        nbuf[pair][lane] = sp * ev;
    }
    __syncthreads();
    if (!noisy) {
        const float logit = mine + nbuf[pair][lane];

        // top-2 across the 8 lanes sharing token t (e lives in lane bits 3..5)
        float v1 = logit, v2 = -INFINITY;
        int   i1 = e,     i2 = 7;
        #pragma unroll
        for (int sm = 3; sm <= 5; ++sm) {
            const int m = 1 << sm;
            const float ov1 = __shfl_xor(v1, m, 64);
            const float ov2 = __shfl_xor(v2, m, 64);
            const int   oi1 = __shfl_xor(i1, m, 64);
            const int   oi2 = __shfl_xor(i2, m, 64);
            // merge two (desc-value, asc-index) sorted pairs
            const bool firstA = (v1 > ov1) || (v1 == ov1 && i1 < oi1);
            const float nv1 = firstA ? v1  : ov1;
            const int   ni1 = firstA ? i1  : oi1;
            const float ca  = firstA ? ov1 : v1;    // losing head
            const int   cia = firstA ? oi1 : i1;
            const float cb  = firstA ? v2  : ov2;   // winner's second
            const int   cib = firstA ? i2  : oi2;
            const bool secondA = (ca > cb) || (ca == cb && cia < cib);
            v1 = nv1; i1 = ni1;
            v2 = secondA ? ca : cb;
            i2 = secondA ? cia : cib;
        }

        if (e == 0) {                       // lanes 0..7, lane == t
            const int tok = tok0 + t;
            out[2 * tok]     = v1;
            out[2 * tok + 1] = v2;
            out[2 * TOKENS + 2 * tok]     = (float)i1;
            out[2 * TOKENS + 2 * tok + 1] = (float)i2;
        }
    }
}

extern "C" void kernel_launch(void* const* d_in, const int* in_sizes, int n_in,
                              void* d_out, int out_size, void* d_ws, size_t ws_size,
                              hipStream_t stream) {
    const float* x       = (const float*)d_in[0];
    const float* w_g     = (const float*)d_in[1];
    const float* w_noise = (const float*)d_in[2];
    const float* eps     = (const float*)d_in[3];
    float* out = (float*)d_out;

    router_kernel<<<GRID, BLOCK, 0, stream>>>(x, w_g, w_noise, eps, out);
}

// Round 8
// 36.697 us; speedup vs baseline: 4.8792x; 4.8792x over previous
//
#include <hip/hip_runtime.h>
#include <math.h>

#define TOKENS 16384
#define DIM 2048
#define NE 8
#define BLOCK 512              // 8 waves = 4 wave-pairs
#define GRID 256               // 256 blocks x 64 tokens
#define NCHUNK (DIM / 256)     // 8 k-chunks of 64 float4
#define NGRP 2                 // token groups per block (4 pairs x 8 tok x 2 = 64)

__launch_bounds__(BLOCK, 2)   // cap VGPR at 256 — V[64]+xv[8]+xn[8] must NOT spill
__global__ void router_kernel(const float* __restrict__ x,
                              const float* __restrict__ w_g,
                              const float* __restrict__ w_noise,
                              const float* __restrict__ eps,
                              float* __restrict__ out)
{
    __shared__ float wlds[16 * DIM];       // 128 KiB: rows 0..7 = w_g, 8..15 = w_noise
    __shared__ float nbuf[NGRP][4][64];    // per-group noise handoff (no extra barrier)

    const int tid = threadIdx.x;

    // ---- stage weights once (coalesced float4) ----
    {
        const float4* g4 = (const float4*)w_g;
        const float4* n4 = (const float4*)w_noise;
        float4* l4 = (float4*)wlds;
        #pragma unroll
        for (int i = tid; i < (NE * DIM) / 4; i += BLOCK) {
            l4[i] = g4[i];
            l4[i + (NE * DIM) / 4] = n4[i];
        }
    }
    __syncthreads();

    const int lane  = tid & 63;
    const int wv    = tid >> 6;        // 0..7
    const int pair  = wv >> 1;         // 0..3
    const int noisy = wv & 1;          // even wave: gate rows; odd: noise rows

    const float4* x4  = (const float4*)x;
    const float4* wl4 = (const float4*)wlds + (noisy ? (NE * DIM / 4) : 0);

    const int e = lane >> 3;           // expert this lane owns post-reduce
    const int t = lane & 7;            // token-in-group this lane owns post-reduce

    for (int g = 0; g < NGRP; ++g) {
        const int tok0 = blockIdx.x * 64 + g * 32 + pair * 8;

        // early eps load (noise wave only) — hides its gather latency under the MLP
        float ev = 0.f;
        if (noisy) ev = eps[(tok0 + t) * NE + e];

        // V[r*8+tt]: partial dot of this wave's row r with token tok0+tt
        float V[64];
        #pragma unroll
        for (int v = 0; v < 64; ++v) V[v] = 0.f;

        float4 xv[8];
        #pragma unroll
        for (int tt = 0; tt < 8; ++tt)
            xv[tt] = x4[(tok0 + tt) * (DIM / 4) + lane];

        #pragma unroll
        for (int k = 0; k < NCHUNK; ++k) {
            float4 xn[8];
            if (k < NCHUNK - 1) {
                #pragma unroll
                for (int tt = 0; tt < 8; ++tt)
                    xn[tt] = x4[(tok0 + tt) * (DIM / 4) + (k + 1) * 64 + lane];
            }
            #pragma unroll
            for (int r = 0; r < 8; ++r) {
                const float4 w = wl4[r * (DIM / 4) + k * 64 + lane];
                #pragma unroll
                for (int tt = 0; tt < 8; ++tt) {
                    float a = V[r * 8 + tt];
                    a = fmaf(xv[tt].x, w.x, a);
                    a = fmaf(xv[tt].y, w.y, a);
                    a = fmaf(xv[tt].z, w.z, a);
                    a = fmaf(xv[tt].w, w.w, a);
                    V[r * 8 + tt] = a;
                }
            }
            if (k < NCHUNK - 1) {
                #pragma unroll
                for (int tt = 0; tt < 8; ++tt) xv[tt] = xn[tt];
            }
        }

        // ---- pack-halving reduction (validated R3/R4): lane L ends with sum of V[L] ----
        #pragma unroll
        for (int s = 0; s < 6; ++s) {
            const int m = 1 << s;
            const int n = 64 >> s;
            #pragma unroll
            for (int j = 0; j < n / 2; ++j) {
                const float A = V[2 * j];
                const float B = V[2 * j + 1];
                const float As = __shfl_xor(A, m, 64);
                const float Bs = __shfl_xor(B, m, 64);
                V[j] = (lane & m) ? (B + Bs) : (A + As);
            }
        }
        const float mine = V[0];       // lane L: row (L>>3)=e, token tok0+(L&7)

        if (noisy) {
            // stable softplus, scale by eps, hand to gate wave via LDS
            const float sp = fmaxf(mine, 0.f) + log1pf(expf(-fabsf(mine)));
            nbuf[g][pair][lane] = sp * ev;
        }
        __syncthreads();
        if (!noisy) {
            const float logit = mine + nbuf[g][pair][lane];

            // top-2 across the 8 lanes sharing token t (e = lane bits 3..5)
            float v1 = logit, v2 = -INFINITY;
            int   i1 = e,     i2 = 7;
            #pragma unroll
            for (int sm = 3; sm <= 5; ++sm) {
                const int m = 1 << sm;
                const float ov1 = __shfl_xor(v1, m, 64);
                const float ov2 = __shfl_xor(v2, m, 64);
                const int   oi1 = __shfl_xor(i1, m, 64);
                const int   oi2 = __shfl_xor(i2, m, 64);
                // merge two (desc-value, asc-index) sorted pairs
                const bool firstA = (v1 > ov1) || (v1 == ov1 && i1 < oi1);
                const float nv1 = firstA ? v1  : ov1;
                const int   ni1 = firstA ? i1  : oi1;
                const float ca  = firstA ? ov1 : v1;    // losing head
                const int   cia = firstA ? oi1 : i1;
                const float cb  = firstA ? v2  : ov2;   // winner's second
                const int   cib = firstA ? i2  : oi2;
                const bool secondA = (ca > cb) || (ca == cb && cia < cib);
                v1 = nv1; i1 = ni1;
                v2 = secondA ? ca : cb;
                i2 = secondA ? cia : cib;
            }

            if (e == 0) {              // lanes 0..7: lane == t
                const int tok = tok0 + t;
                *(float2*)&out[2 * tok] = make_float2(v1, v2);
                *(float2*)&out[2 * TOKENS + 2 * tok] = make_float2((float)i1, (float)i2);
            }
        }
    }
}

extern "C" void kernel_launch(void* const* d_in, const int* in_sizes, int n_in,
                              void* d_out, int out_size, void* d_ws, size_t ws_size,
                              hipStream_t stream) {
    const float* x       = (const float*)d_in[0];
    const float* w_g     = (const float*)d_in[1];
    const float* w_noise = (const float*)d_in[2];
    const float* eps     = (const float*)d_in[3];
    float* out = (float*)d_out;

    router_kernel<<<GRID, BLOCK, 0, stream>>>(x, w_g, w_noise, eps, out);
}

// Round 9
// 34.855 us; speedup vs baseline: 5.1370x; 1.0528x over previous
//
#include <hip/hip_runtime.h>
#include <math.h>

#define TOKENS 16384
#define DIM 2048
#define NE 8
#define BLOCK 1024             // 16 waves = 4 quads
#define GRID 256               // 256 blocks x 64 tokens
#define NCHUNK (DIM / 256)     // 8 k-chunks of 64 float4
#define NGRP 2                 // 4 quads x 8 tok x 2 groups = 64 tokens/block

__launch_bounds__(BLOCK, 4)   // cap VGPR at 128; V[32]+xv[8]+w fits ~100-120
__global__ void router_kernel(const float* __restrict__ x,
                              const float* __restrict__ w_g,
                              const float* __restrict__ w_noise,
                              const float* __restrict__ eps,
                              float* __restrict__ out)
{
    __shared__ float wlds[16 * DIM];            // 128 KiB: rows 0..7 w_g, 8..15 w_noise
    __shared__ float lbuf[NGRP][4][2][NE][8];   // [grp][quad][gate|noise][e][t] = 4 KiB

    const int tid = threadIdx.x;

    // ---- stage weights once (coalesced float4) ----
    {
        const float4* g4 = (const float4*)w_g;
        const float4* n4 = (const float4*)w_noise;
        float4* l4 = (float4*)wlds;
        for (int i = tid; i < (NE * DIM) / 4; i += BLOCK) {
            l4[i] = g4[i];
            l4[i + (NE * DIM) / 4] = n4[i];
        }
    }
    __syncthreads();

    const int lane    = tid & 63;
    const int wv      = tid >> 6;        // 0..15
    const int quad    = wv >> 2;         // 0..3 (8 tokens each)
    const int noisy   = (wv >> 1) & 1;   // 0: gate rows, 1: noise rows
    const int rowhalf = wv & 1;          // 0: experts 0-3, 1: experts 4-7

    const float4* x4  = (const float4*)x;
    const float4* wl4 = (const float4*)wlds + (noisy * NE + rowhalf * 4) * (DIM / 4);

    const int eloc = (lane >> 3) & 3;    // local row this lane owns post-reduce
    const int e    = rowhalf * 4 + eloc; // global expert row
    const int t    = lane & 7;           // token-in-quad this lane owns post-reduce

    for (int g = 0; g < NGRP; ++g) {
        const int tok0 = blockIdx.x * 64 + g * 32 + quad * 8;

        // early eps load (noise waves, lanes<32) — latency hides under the MLP
        float ev = 0.f;
        if (noisy && lane < 32) ev = eps[(tok0 + t) * NE + e];

        // V[r*8+tt]: partial dot of row (rowbase+r) with token tok0+tt
        float V[32];
        #pragma unroll
        for (int v = 0; v < 32; ++v) V[v] = 0.f;

        #pragma unroll 2                 // bounded unroll: keep loads in flight w/o spill
        for (int k = 0; k < NCHUNK; ++k) {
            float4 xv[8];
            #pragma unroll
            for (int tt = 0; tt < 8; ++tt)
                xv[tt] = x4[(tok0 + tt) * (DIM / 4) + k * 64 + lane];
            #pragma unroll
            for (int r = 0; r < 4; ++r) {
                const float4 w = wl4[r * (DIM / 4) + k * 64 + lane];
                #pragma unroll
                for (int tt = 0; tt < 8; ++tt) {
                    float a = V[r * 8 + tt];
                    a = fmaf(xv[tt].x, w.x, a);
                    a = fmaf(xv[tt].y, w.y, a);
                    a = fmaf(xv[tt].z, w.z, a);
                    a = fmaf(xv[tt].w, w.w, a);
                    V[r * 8 + tt] = a;
                }
            }
        }

        // ---- pack-halving: 5 steps over 32 values, xor-32 completes the lane sum ----
        #pragma unroll
        for (int s = 0; s < 5; ++s) {
            const int m = 1 << s;
            const int n = 32 >> s;
            #pragma unroll
            for (int j = 0; j < n / 2; ++j) {
                const float A = V[2 * j];
                const float B = V[2 * j + 1];
                const float As = __shfl_xor(A, m, 64);
                const float Bs = __shfl_xor(B, m, 64);
                V[j] = (lane & m) ? (B + Bs) : (A + As);
            }
        }
        const float mine = V[0] + __shfl_xor(V[0], 32, 64);
        // lane L: value (r=(L>>3)&3, t=L&7), fully summed

        if (lane < 32) {
            if (noisy) {
                const float sp = fmaxf(mine, 0.f) + log1pf(expf(-fabsf(mine)));
                lbuf[g][quad][1][e][t] = sp * ev;   // noise contribution
            } else {
                lbuf[g][quad][0][e][t] = mine;      // gate logit
            }
        }
        __syncthreads();

        if ((wv & 3) == 0) {             // wave 0 of each quad: top-2 over 8 experts
            const int te = lane >> 3;    // expert 0..7 (lane bits 3-5)
            const float logit = lbuf[g][quad][0][te][t] + lbuf[g][quad][1][te][t];

            float v1 = logit, v2 = -INFINITY;
            int   i1 = te,    i2 = 7;
            #pragma unroll
            for (int sm = 3; sm <= 5; ++sm) {
                const int m = 1 << sm;
                const float ov1 = __shfl_xor(v1, m, 64);
                const float ov2 = __shfl_xor(v2, m, 64);
                const int   oi1 = __shfl_xor(i1, m, 64);
                const int   oi2 = __shfl_xor(i2, m, 64);
                // merge two (desc-value, asc-index) sorted pairs
                const bool firstA = (v1 > ov1) || (v1 == ov1 && i1 < oi1);
                const float nv1 = firstA ? v1  : ov1;
                const int   ni1 = firstA ? i1  : oi1;
                const float ca  = firstA ? ov1 : v1;    // losing head
                const int   cia = firstA ? oi1 : i1;
                const float cb  = firstA ? v2  : ov2;   // winner's second
                const int   cib = firstA ? i2  : oi2;
                const bool secondA = (ca > cb) || (ca == cb && cia < cib);
                v1 = nv1; i1 = ni1;
                v2 = secondA ? ca : cb;
                i2 = secondA ? cia : cib;
            }

            if (te == 0) {               // lanes 0..7: lane == t
                const int tok = tok0 + t;
                *(float2*)&out[2 * tok] = make_float2(v1, v2);
                *(float2*)&out[2 * TOKENS + 2 * tok] = make_float2((float)i1, (float)i2);
            }
        }
        // no extra barrier: next group writes lbuf[g^1], disjoint from this read
    }
}

extern "C" void kernel_launch(void* const* d_in, const int* in_sizes, int n_in,
                              void* d_out, int out_size, void* d_ws, size_t ws_size,
                              hipStream_t stream) {
    const float* x       = (const float*)d_in[0];
    const float* w_g     = (const float*)d_in[1];
    const float* w_noise = (const float*)d_in[2];
    const float* eps     = (const float*)d_in[3];
    float* out = (float*)d_out;

    router_kernel<<<GRID, BLOCK, 0, stream>>>(x, w_g, w_noise, eps, out);
}

// Round 10
// 34.753 us; speedup vs baseline: 5.1521x; 1.0029x over previous
//
#include <hip/hip_runtime.h>
#include <math.h>

#define TOKENS 16384
#define DIM 2048
#define NE 8
#define BLOCK 1024             // 16 waves, 1 block/CU (128 KiB LDS)
#define GRID 256
#define NCHUNK (DIM / 256)     // 8 chunks of 64 float4

__launch_bounds__(BLOCK, 4)   // VGPR cap 128: V[64]+xvA[4]+xvB[4] ~= 118, no spill
__global__ void router_kernel(const float* __restrict__ x,
                              const float* __restrict__ w_g,
                              const float* __restrict__ w_noise,
                              const float* __restrict__ eps,
                              float* __restrict__ out)
{
    __shared__ float wlds[16 * DIM];   // rows 0..7 = w_g, 8..15 = w_noise

    const int tid  = threadIdx.x;
    const int lane = tid & 63;
    const int wv   = tid >> 6;                   // 0..15
    const int t0   = (blockIdx.x * 16 + wv) * 4; // this wave's 4 tokens

    const float4* x4 = (const float4*)x;

    // ---- (1) issue x chunk-0/1 loads FIRST: latency overlaps weight staging ----
    float4 xvA[4], xvB[4];
    #pragma unroll
    for (int t = 0; t < 4; ++t) xvA[t] = x4[(t0 + t) * (DIM / 4) + 0 * 64 + lane];
    #pragma unroll
    for (int t = 0; t < 4; ++t) xvB[t] = x4[(t0 + t) * (DIM / 4) + 1 * 64 + lane];

    // early eps (lanes<32): eps[t0*8 .. t0*8+31] for this wave's 4 tokens
    float my_eps = 0.f;
    if (lane < 32) my_eps = eps[t0 * NE + lane];

    // ---- stage weights (coalesced float4) ----
    {
        const float4* g4 = (const float4*)w_g;
        const float4* n4 = (const float4*)w_noise;
        float4* l4 = (float4*)wlds;
        #pragma unroll
        for (int i = tid; i < (NE * DIM) / 4; i += BLOCK) {
            l4[i] = g4[i];
            l4[i + (NE * DIM) / 4] = n4[i];
        }
    }
    __syncthreads();

    const float4* wl4 = (const float4*)wlds;

    // V[r*4+t]: partial dot of row r (0..15) with token t0+t
    float V[64];
    #pragma unroll
    for (int v = 0; v < 64; ++v) V[v] = 0.f;

    // ---- (2) k-loop unrolled x2: consume buffer, then refill for k+2 ----
    #pragma unroll
    for (int kp = 0; kp < NCHUNK; kp += 2) {
        // body A: chunk kp from xvA
        #pragma unroll
        for (int r = 0; r < 16; ++r) {
            const float4 w = wl4[r * (DIM / 4) + kp * 64 + lane];
            #pragma unroll
            for (int t = 0; t < 4; ++t) {
                float a = V[r * 4 + t];
                a = fmaf(xvA[t].x, w.x, a);
                a = fmaf(xvA[t].y, w.y, a);
                a = fmaf(xvA[t].z, w.z, a);
                a = fmaf(xvA[t].w, w.w, a);
                V[r * 4 + t] = a;
            }
        }
        if (kp + 2 < NCHUNK) {          // refill A with chunk kp+2 (in flight ~2 bodies)
            #pragma unroll
            for (int t = 0; t < 4; ++t)
                xvA[t] = x4[(t0 + t) * (DIM / 4) + (kp + 2) * 64 + lane];
        }
        // body B: chunk kp+1 from xvB
        #pragma unroll
        for (int r = 0; r < 16; ++r) {
            const float4 w = wl4[r * (DIM / 4) + (kp + 1) * 64 + lane];
            #pragma unroll
            for (int t = 0; t < 4; ++t) {
                float a = V[r * 4 + t];
                a = fmaf(xvB[t].x, w.x, a);
                a = fmaf(xvB[t].y, w.y, a);
                a = fmaf(xvB[t].z, w.z, a);
                a = fmaf(xvB[t].w, w.w, a);
                V[r * 4 + t] = a;
            }
        }
        if (kp + 3 < NCHUNK) {          // refill B with chunk kp+3
            #pragma unroll
            for (int t = 0; t < 4; ++t)
                xvB[t] = x4[(t0 + t) * (DIM / 4) + (kp + 3) * 64 + lane];
        }
    }

    // ---- pack-halving reduction (validated R3): lane L ends with sum of V[L] ----
    #pragma unroll
    for (int s = 0; s < 6; ++s) {
        const int m = 1 << s;
        const int n = 64 >> s;
        #pragma unroll
        for (int j = 0; j < n / 2; ++j) {
            const float A = V[2 * j];
            const float B = V[2 * j + 1];
            const float As = __shfl_xor(A, m, 64);
            const float Bs = __shfl_xor(B, m, 64);
            V[j] = (lane & m) ? (B + Bs) : (A + As);
        }
    }
    const float mine = V[0];            // lane L: row (L>>2), token t0+(L&3)

    // lanes <32 hold gate sums (rows 0..7); lane+32 holds matching noise sum
    const float other = __shfl_xor(mine, 32, 64);

    if (lane < 32) {
        const int e = lane >> 2;
        const int t = lane & 3;
        const int tok = t0 + t;

        // eps[t*8+e] is held by lane (t<<3)|e
        const float ev = __shfl(my_eps, (t << 3) | e, 64);

        const float nv = other;
        const float sp = fmaxf(nv, 0.f) + log1pf(expf(-fabsf(nv)));  // stable softplus
        const float logit = fmaf(sp, ev, mine);

        // top-2 across the 8 lanes sharing token t (e lives in lane bits 2..4)
        float v1 = logit, v2 = -INFINITY;
        int   i1 = e,     i2 = 7;
        #pragma unroll
        for (int sm = 2; sm <= 4; ++sm) {
            const int m = 1 << sm;
            const float ov1 = __shfl_xor(v1, m, 64);
            const float ov2 = __shfl_xor(v2, m, 64);
            const int   oi1 = __shfl_xor(i1, m, 64);
            const int   oi2 = __shfl_xor(i2, m, 64);
            // merge two (desc-value, asc-index) sorted pairs
            const bool firstA = (v1 > ov1) || (v1 == ov1 && i1 < oi1);
            const float nv1 = firstA ? v1  : ov1;
            const int   ni1 = firstA ? i1  : oi1;
            const float ca  = firstA ? ov1 : v1;    // losing head
            const int   cia = firstA ? oi1 : i1;
            const float cb  = firstA ? v2  : ov2;   // winner's second
            const int   cib = firstA ? i2  : oi2;
            const bool secondA = (ca > cb) || (ca == cb && cia < cib);
            v1 = nv1; i1 = ni1;
            v2 = secondA ? ca : cb;
            i2 = secondA ? cia : cib;
        }

        if (e == 0) {                   // lanes 0..3: lane == t
            *(float2*)&out[2 * tok] = make_float2(v1, v2);
            *(float2*)&out[2 * TOKENS + 2 * tok] = make_float2((float)i1, (float)i2);
        }
    }
}

extern "C" void kernel_launch(void* const* d_in, const int* in_sizes, int n_in,
                              void* d_out, int out_size, void* d_ws, size_t ws_size,
                              hipStream_t stream) {
    const float* x       = (const float*)d_in[0];
    const float* w_g     = (const float*)d_in[1];
    const float* w_noise = (const float*)d_in[2];
    const float* eps     = (const float*)d_in[3];
    float* out = (float*)d_out;

    router_kernel<<<GRID, BLOCK, 0, stream>>>(x, w_g, w_noise, eps, out);
}

// Round 11
// 33.302 us; speedup vs baseline: 5.3767x; 1.0436x over previous
//
#include <hip/hip_runtime.h>
#include <math.h>

#define TOKENS 16384
#define DIM 2048
#define NE 8
#define BLOCK 1024             // 16 waves, 1 block/CU (128 KiB LDS)
#define GRID 256
#define NCHUNK (DIM / 256)     // 8 chunks of 64 float4

__launch_bounds__(BLOCK, 4)   // VGPR cap 128: V[64]+xvA[4]+xvB[4] ~= 118, no spill
__global__ void router_kernel(const float* __restrict__ x,
                              const float* __restrict__ w_g,
                              const float* __restrict__ w_noise,
                              const float* __restrict__ eps,
                              float* __restrict__ out)
{
    __shared__ float wlds[16 * DIM];   // rows 0..7 = w_g, 8..15 = w_noise

    const int tid  = threadIdx.x;
    const int lane = tid & 63;
    const int wv   = tid >> 6;                   // 0..15
    const int t0   = (blockIdx.x * 16 + wv) * 4; // this wave's 4 tokens

    // convoy-breaker: per-wave chunk phase (waves on a SIMD differ by 2 chunks)
    const int off  = (wv & 3) * 2;
    // chunk index for logical step i: c(i) = (i + off) & 7

    const float4* x4 = (const float4*)x;

    // ---- issue x loads for steps 0/1 FIRST: latency overlaps weight staging ----
    float4 xvA[4], xvB[4];
    {
        const int c0 = off;              // c(0)
        const int c1 = (1 + off) & 7;    // c(1)
        #pragma unroll
        for (int t = 0; t < 4; ++t) xvA[t] = x4[(t0 + t) * (DIM / 4) + c0 * 64 + lane];
        #pragma unroll
        for (int t = 0; t < 4; ++t) xvB[t] = x4[(t0 + t) * (DIM / 4) + c1 * 64 + lane];
    }

    // early eps (lanes<32): eps[t0*8 .. t0*8+31] for this wave's 4 tokens
    float my_eps = 0.f;
    if (lane < 32) my_eps = eps[t0 * NE + lane];

    // ---- stage weights (coalesced float4) ----
    {
        const float4* g4 = (const float4*)w_g;
        const float4* n4 = (const float4*)w_noise;
        float4* l4 = (float4*)wlds;
        #pragma unroll
        for (int i = tid; i < (NE * DIM) / 4; i += BLOCK) {
            l4[i] = g4[i];
            l4[i + (NE * DIM) / 4] = n4[i];
        }
    }
    __syncthreads();

    const float4* wl4 = (const float4*)wlds;

    // V[r*4+t]: partial dot of row r (0..15) with token t0+t
    float V[64];
    #pragma unroll
    for (int v = 0; v < 64; ++v) V[v] = 0.f;

    // ---- k-loop over logical steps, chunk = (i+off)&7, unrolled x2 ----
    #pragma unroll
    for (int i = 0; i < NCHUNK; i += 2) {
        const int kA = (i + off) & 7;          // consumed from xvA
        const int kB = (i + 1 + off) & 7;      // consumed from xvB

        // body A: chunk kA
        #pragma unroll
        for (int r = 0; r < 16; ++r) {
            const float4 w = wl4[r * (DIM / 4) + kA * 64 + lane];
            #pragma unroll
            for (int t = 0; t < 4; ++t) {
                float a = V[r * 4 + t];
                a = fmaf(xvA[t].x, w.x, a);
                a = fmaf(xvA[t].y, w.y, a);
                a = fmaf(xvA[t].z, w.z, a);
                a = fmaf(xvA[t].w, w.w, a);
                V[r * 4 + t] = a;
            }
        }
        if (i + 2 < NCHUNK) {                  // refill A with chunk c(i+2)
            const int kN = (i + 2 + off) & 7;
            #pragma unroll
            for (int t = 0; t < 4; ++t)
                xvA[t] = x4[(t0 + t) * (DIM / 4) + kN * 64 + lane];
        }
        // body B: chunk kB
        #pragma unroll
        for (int r = 0; r < 16; ++r) {
            const float4 w = wl4[r * (DIM / 4) + kB * 64 + lane];
            #pragma unroll
            for (int t = 0; t < 4; ++t) {
                float a = V[r * 4 + t];
                a = fmaf(xvB[t].x, w.x, a);
                a = fmaf(xvB[t].y, w.y, a);
                a = fmaf(xvB[t].z, w.z, a);
                a = fmaf(xvB[t].w, w.w, a);
                V[r * 4 + t] = a;
            }
        }
        if (i + 3 < NCHUNK) {                  // refill B with chunk c(i+3)
            const int kN = (i + 3 + off) & 7;
            #pragma unroll
            for (int t = 0; t < 4; ++t)
                xvB[t] = x4[(t0 + t) * (DIM / 4) + kN * 64 + lane];
        }
    }

    // ---- pack-halving reduction (validated R3): lane L ends with sum of V[L] ----
    #pragma unroll
    for (int s = 0; s < 6; ++s) {
        const int m = 1 << s;
        const int n = 64 >> s;
        #pragma unroll
        for (int j = 0; j < n / 2; ++j) {
            const float A = V[2 * j];
            const float B = V[2 * j + 1];
            const float As = __shfl_xor(A, m, 64);
            const float Bs = __shfl_xor(B, m, 64);
            V[j] = (lane & m) ? (B + Bs) : (A + As);
        }
    }
    const float mine = V[0];            // lane L: row (L>>2), token t0+(L&3)

    // lanes <32 hold gate sums (rows 0..7); lane+32 holds matching noise sum
    const float other = __shfl_xor(mine, 32, 64);

    if (lane < 32) {
        const int e = lane >> 2;
        const int t = lane & 3;
        const int tok = t0 + t;

        // eps[t*8+e] is held by lane (t<<3)|e
        const float ev = __shfl(my_eps, (t << 3) | e, 64);

        const float nv = other;
        const float sp = fmaxf(nv, 0.f) + log1pf(expf(-fabsf(nv)));  // stable softplus
        const float logit = fmaf(sp, ev, mine);

        // top-2 across the 8 lanes sharing token t (e lives in lane bits 2..4)
        float v1 = logit, v2 = -INFINITY;
        int   i1 = e,     i2 = 7;
        #pragma unroll
        for (int sm = 2; sm <= 4; ++sm) {
            const int m = 1 << sm;
            const float ov1 = __shfl_xor(v1, m, 64);
            const float ov2 = __shfl_xor(v2, m, 64);
            const int   oi1 = __shfl_xor(i1, m, 64);
            const int   oi2 = __shfl_xor(i2, m, 64);
            // merge two (desc-value, asc-index) sorted pairs
            const bool firstA = (v1 > ov1) || (v1 == ov1 && i1 < oi1);
            const float nv1 = firstA ? v1  : ov1;
            const int   ni1 = firstA ? i1  : oi1;
            const float ca  = firstA ? ov1 : v1;    // losing head
            const int   cia = firstA ? oi1 : i1;
            const float cb  = firstA ? v2  : ov2;   // winner's second
            const int   cib = firstA ? i2  : oi2;
            const bool secondA = (ca > cb) || (ca == cb && cia < cib);
            v1 = nv1; i1 = ni1;
            v2 = secondA ? ca : cb;
            i2 = secondA ? cia : cib;
        }

        if (e == 0) {                   // lanes 0..3: lane == t
            *(float2*)&out[2 * tok] = make_float2(v1, v2);
            *(float2*)&out[2 * TOKENS + 2 * tok] = make_float2((float)i1, (float)i2);
        }
    }
}

extern "C" void kernel_launch(void* const* d_in, const int* in_sizes, int n_in,
                              void* d_out, int out_size, void* d_ws, size_t ws_size,
                              hipStream_t stream) {
    const float* x       = (const float*)d_in[0];
    const float* w_g     = (const float*)d_in[1];
    const float* w_noise = (const float*)d_in[2];
    const float* eps     = (const float*)d_in[3];
    float* out = (float*)d_out;

    router_kernel<<<GRID, BLOCK, 0, stream>>>(x, w_g, w_noise, eps, out);
}